// Round 4
// baseline (138.578 us; speedup 1.0000x reference)
//
#include <hip/hip_runtime.h>

// CenterLoss: loss = sum_i ||pred_i - centers[t_i]||^2 + BATCH*(NUM_CLASSES-1)*1e-12.
// (clamp [1e-12,1e12] provably inert for N(0,1) data: dist ~ 2048 +- ~90.)
// pred: [16384,1024] f32, centers: [10000,1024] f32, target: [16384] int.
// R3 fix: __builtin_nontemporal_load needs a native vector type, not
// HIP_vector_type<float,4> -> use clang ext_vector_type(4) float.

constexpr int BATCH = 16384;
constexpr int FEAT = 1024;
constexpr int NUM_CLASSES = 10000;
constexpr int NBLOCKS = 2048;   // 8 blocks/CU on 256 CUs; 4 waves/block, 2 rows/wave

typedef float vf4 __attribute__((ext_vector_type(4)));

__global__ void cl_init(float* __restrict__ out) {
    out[0] = (float)((double)BATCH * (double)(NUM_CLASSES - 1) * 1e-12);
}

__global__ __launch_bounds__(256) void cl_main(const float* __restrict__ pred,
                                               const float* __restrict__ centers,
                                               const int* __restrict__ target,
                                               float* __restrict__ out) {
    const int lane  = (int)(threadIdx.x & 63u);
    const int wave  = (int)(threadIdx.x >> 6);
    const int gwave = (int)blockIdx.x * 4 + wave;   // 8192 waves, 2 rows each

    const int r0 = gwave * 2;
    const int r1 = r0 + 1;
    const int t0 = target[r0];   // wave-uniform broadcast loads, issued first
    const int t1 = target[r1];

    const vf4* p0 = reinterpret_cast<const vf4*>(pred    + (size_t)r0 * FEAT) + lane;
    const vf4* p1 = reinterpret_cast<const vf4*>(pred    + (size_t)r1 * FEAT) + lane;
    const vf4* c0 = reinterpret_cast<const vf4*>(centers + (size_t)t0 * FEAT) + lane;
    const vf4* c1 = reinterpret_cast<const vf4*>(centers + (size_t)t1 * FEAT) + lane;

    // 64 lanes x 4 vf4 = the full 1024-float row, coalesced 16 B/lane.
    // 16 independent loads in flight; pred is streamed once -> nontemporal
    // so the centers gather keeps L2/L3 residency.
    float s = 0.0f;
#pragma unroll
    for (int j = 0; j < 4; ++j) {
        const vf4 a0 = __builtin_nontemporal_load(&p0[64 * j]);
        const vf4 b0 = c0[64 * j];
        const vf4 a1 = __builtin_nontemporal_load(&p1[64 * j]);
        const vf4 b1 = c1[64 * j];
        const vf4 d0 = a0 - b0;
        const vf4 d1 = a1 - b1;
        s = fmaf(d0.x, d0.x, s);
        s = fmaf(d0.y, d0.y, s);
        s = fmaf(d0.z, d0.z, s);
        s = fmaf(d0.w, d0.w, s);
        s = fmaf(d1.x, d1.x, s);
        s = fmaf(d1.y, d1.y, s);
        s = fmaf(d1.z, d1.z, s);
        s = fmaf(d1.w, d1.w, s);
    }

    // one reduction per block: wave butterfly -> LDS -> thread 0 -> one atomic
#pragma unroll
    for (int off = 32; off > 0; off >>= 1)
        s += __shfl_xor(s, off, 64);

    __shared__ float red[4];
    if (lane == 0) red[wave] = s;
    __syncthreads();
    if (threadIdx.x == 0)
        atomicAdd(out, red[0] + red[1] + red[2] + red[3]);  // 2048 total, device-scope
}

extern "C" void kernel_launch(void* const* d_in, const int* in_sizes, int n_in,
                              void* d_out, int out_size, void* d_ws, size_t ws_size,
                              hipStream_t stream) {
    const float* pred    = (const float*)d_in[0];
    const float* centers = (const float*)d_in[1];
    const int*   target  = (const int*)d_in[2];
    float*       out     = (float*)d_out;

    cl_init<<<1, 1, 0, stream>>>(out);
    cl_main<<<NBLOCKS, 256, 0, stream>>>(pred, centers, target, out);
}

// Round 5
// 129.345 us; speedup vs baseline: 1.0714x; 1.0714x over previous
//
#include <hip/hip_runtime.h>

// CenterLoss: loss = sum_i ||pred_i - centers[t_i]||^2 + BATCH*(NUM_CLASSES-1)*1e-12.
// (clamp [1e-12,1e12] provably inert for N(0,1) data: dist ~ 2048 +- ~90.)
// pred: [16384,1024] f32, centers: [10000,1024] f32, target: [16384] int.
//
// R5: R1/R4's one-shot burst waves (16 loads, reduce, exit) never sustain
// memory issue and pay ramp/drain on 2048 tiny blocks -> persistent-style:
// 1024 blocks, 4 rows/wave with register double-buffer prefetch (row k+1's
// 8 loads issued before row k is consumed), 1024 atomics instead of 2048.

constexpr int BATCH = 16384;
constexpr int FEAT = 1024;
constexpr int NUM_CLASSES = 10000;
constexpr int ROWS_PER_WAVE = 4;
constexpr int NBLOCKS = BATCH / (4 * ROWS_PER_WAVE);  // 1024 blocks, 4 waves each

typedef float vf4 __attribute__((ext_vector_type(4)));

__global__ void cl_init(float* __restrict__ out) {
    // overwrites harness 0xAA poison; masked-out clamp entries contribute this constant
    out[0] = (float)((double)BATCH * (double)(NUM_CLASSES - 1) * 1e-12);
}

__global__ __launch_bounds__(256) void cl_main(const float* __restrict__ pred,
                                               const float* __restrict__ centers,
                                               const int* __restrict__ target,
                                               float* __restrict__ out) {
    const int lane  = (int)(threadIdx.x & 63u);
    const int wave  = (int)(threadIdx.x >> 6);
    const int gwave = (int)blockIdx.x * 4 + wave;          // 4096 waves
    const int row0  = gwave * ROWS_PER_WAVE;

    // all 4 targets up front (wave-uniform, contiguous)
    int t[ROWS_PER_WAVE];
#pragma unroll
    for (int k = 0; k < ROWS_PER_WAVE; ++k) t[k] = target[row0 + k];

    // register double-buffer: 8 loads (4 pred + 4 center vf4) per row, 16 B/lane coalesced
    vf4 pa[2][4], ca[2][4];

    auto issue = [&](int k, int buf) {
        const vf4* p = reinterpret_cast<const vf4*>(pred    + (size_t)(row0 + k) * FEAT) + lane;
        const vf4* c = reinterpret_cast<const vf4*>(centers + (size_t)t[k]       * FEAT) + lane;
#pragma unroll
        for (int j = 0; j < 4; ++j) {
            pa[buf][j] = __builtin_nontemporal_load(&p[64 * j]);  // pred streamed once
            ca[buf][j] = c[64 * j];                               // centers: keep cacheable
        }
    };

    issue(0, 0);  // prologue

    float s0 = 0.0f, s1 = 0.0f;   // 2 accumulators: halve FMA dep-chain
#pragma unroll
    for (int k = 0; k < ROWS_PER_WAVE; ++k) {
        const int cur = k & 1;
        if (k + 1 < ROWS_PER_WAVE) issue(k + 1, (k + 1) & 1);  // prefetch next row
#pragma unroll
        for (int j = 0; j < 4; ++j) {
            const vf4 d = pa[cur][j] - ca[cur][j];
            s0 = fmaf(d.x, d.x, s0);
            s1 = fmaf(d.y, d.y, s1);
            s0 = fmaf(d.z, d.z, s0);
            s1 = fmaf(d.w, d.w, s1);
        }
    }
    float s = s0 + s1;

    // one reduction per block: wave butterfly -> LDS -> thread 0 -> one atomic
#pragma unroll
    for (int off = 32; off > 0; off >>= 1)
        s += __shfl_xor(s, off, 64);

    __shared__ float red[4];
    if (lane == 0) red[wave] = s;
    __syncthreads();
    if (threadIdx.x == 0)
        atomicAdd(out, red[0] + red[1] + red[2] + red[3]);  // 1024 total, device-scope
}

extern "C" void kernel_launch(void* const* d_in, const int* in_sizes, int n_in,
                              void* d_out, int out_size, void* d_ws, size_t ws_size,
                              hipStream_t stream) {
    const float* pred    = (const float*)d_in[0];
    const float* centers = (const float*)d_in[1];
    const int*   target  = (const int*)d_in[2];
    float*       out     = (float*)d_out;

    cl_init<<<1, 1, 0, stream>>>(out);
    cl_main<<<NBLOCKS, 256, 0, stream>>>(pred, centers, target, out);
}

// Round 6
// 124.583 us; speedup vs baseline: 1.1123x; 1.0382x over previous
//
#include <hip/hip_runtime.h>

// CenterLoss: loss = sum_i ||pred_i - centers[t_i]||^2 + BATCH*(NUM_CLASSES-1)*1e-12.
// (clamp [1e-12,1e12] provably inert for N(0,1) data: dist ~ 2048 +- ~90.)
// pred: [16384,1024] f32, centers: [10000,1024] f32, target: [16384] int.
//
// R6: R5's 1024 co-resident blocks finish near-simultaneously -> 1024
// same-address device-scope atomicAdds arrive as a burst, serializing at one
// L2 slice across 8 XCDs. Fix: per-block partials to d_ws (plain stores) +
// tiny finalize kernel (also folds the masked constant; cl_init deleted).
// 512 blocks x 4 waves x 8 rows/wave, register double-buffer prefetch.

constexpr int BATCH = 16384;
constexpr int FEAT = 1024;
constexpr int NUM_CLASSES = 10000;
constexpr int ROWS_PER_WAVE = 8;
constexpr int NBLOCKS = BATCH / (4 * ROWS_PER_WAVE);  // 512 blocks, 2/CU

typedef float vf4 __attribute__((ext_vector_type(4)));

__global__ __launch_bounds__(256) void cl_main(const float* __restrict__ pred,
                                               const float* __restrict__ centers,
                                               const int* __restrict__ target,
                                               float* __restrict__ partials) {
    const int lane  = (int)(threadIdx.x & 63u);
    const int wave  = (int)(threadIdx.x >> 6);
    const int gwave = (int)blockIdx.x * 4 + wave;          // 2048 waves
    const int row0  = gwave * ROWS_PER_WAVE;

    // all 8 targets up front (wave-uniform, contiguous -> scalar loads)
    int t[ROWS_PER_WAVE];
#pragma unroll
    for (int k = 0; k < ROWS_PER_WAVE; ++k) t[k] = target[row0 + k];

    // register double-buffer: 8 loads (4 pred + 4 center vf4) per row, 16 B/lane
    vf4 pa[2][4], ca[2][4];

    auto issue = [&](int k, int buf) {
        const vf4* p = reinterpret_cast<const vf4*>(pred    + (size_t)(row0 + k) * FEAT) + lane;
        const vf4* c = reinterpret_cast<const vf4*>(centers + (size_t)t[k]       * FEAT) + lane;
#pragma unroll
        for (int j = 0; j < 4; ++j) {
            pa[buf][j] = __builtin_nontemporal_load(&p[64 * j]);  // pred: streamed once
            ca[buf][j] = c[64 * j];                               // centers: cacheable
        }
    };

    issue(0, 0);  // prologue

    float s0 = 0.0f, s1 = 0.0f;   // 2 accumulators: halve FMA dep-chain
#pragma unroll
    for (int k = 0; k < ROWS_PER_WAVE; ++k) {
        const int cur = k & 1;
        if (k + 1 < ROWS_PER_WAVE) issue(k + 1, (k + 1) & 1);  // prefetch next row
#pragma unroll
        for (int j = 0; j < 4; ++j) {
            const vf4 d = pa[cur][j] - ca[cur][j];
            s0 = fmaf(d.x, d.x, s0);
            s1 = fmaf(d.y, d.y, s1);
            s0 = fmaf(d.z, d.z, s0);
            s1 = fmaf(d.w, d.w, s1);
        }
    }
    float s = s0 + s1;

    // one reduction per block: wave butterfly -> LDS -> thread 0 -> plain store
#pragma unroll
    for (int off = 32; off > 0; off >>= 1)
        s += __shfl_xor(s, off, 64);

    __shared__ float red[4];
    if (lane == 0) red[wave] = s;
    __syncthreads();
    if (threadIdx.x == 0)
        partials[blockIdx.x] = red[0] + red[1] + red[2] + red[3];  // no atomics
}

__global__ __launch_bounds__(256) void cl_finalize(const float* __restrict__ partials,
                                                   float* __restrict__ out) {
    // 512 partials: 2 per thread (all were written by cl_main; d_ws poison untouched)
    float s = partials[threadIdx.x] + partials[threadIdx.x + 256];

#pragma unroll
    for (int off = 32; off > 0; off >>= 1)
        s += __shfl_xor(s, off, 64);

    __shared__ float red[4];
    if ((threadIdx.x & 63u) == 0) red[threadIdx.x >> 6] = s;
    __syncthreads();
    if (threadIdx.x == 0) {
        const float masked_const = (float)((double)BATCH * (double)(NUM_CLASSES - 1) * 1e-12);
        out[0] = red[0] + red[1] + red[2] + red[3] + masked_const;
    }
}

extern "C" void kernel_launch(void* const* d_in, const int* in_sizes, int n_in,
                              void* d_out, int out_size, void* d_ws, size_t ws_size,
                              hipStream_t stream) {
    const float* pred    = (const float*)d_in[0];
    const float* centers = (const float*)d_in[1];
    const int*   target  = (const int*)d_in[2];
    float*       out     = (float*)d_out;
    float*       partials = (float*)d_ws;   // 512 floats, fully written before read

    cl_main<<<NBLOCKS, 256, 0, stream>>>(pred, centers, target, partials);
    cl_finalize<<<1, 256, 0, stream>>>(partials, out);
}